// Round 20
// baseline (444.911 us; speedup 1.0000x reference)
//
#include <hip/hip_runtime.h>
#include <math.h>

#define LEVELS 16
#define MAX_RES 2048
#define NCELL_BITS 6
#define NCELLS (1 << (3 * NCELL_BITS))   // 262144 cells (64^3), ~4 points/cell
#define NSEG   (NCELLS / 256)            // 1024 scan segments
#define LC_LO 9
#define LC_HI 12
#define NLC (LC_HI - LC_LO + 1)

typedef float nfloat4 __attribute__((ext_vector_type(4)));
typedef float nfloat2 __attribute__((ext_vector_type(2)));

struct ResParams {
  int res[LEVELS];
  int coff[LEVELS];
  int S[LEVELS];
  int bstart[NLC + 1];
};

// ---------------- sort helpers ----------------

__device__ __forceinline__ unsigned int morton6(int cx, int cy, int cz) {
  unsigned int k = 0;
  #pragma unroll
  for (int b = 0; b < NCELL_BITS; ++b)
    k |= (((cx >> b) & 1) << (3 * b)) | (((cy >> b) & 1) << (3 * b + 1)) |
         (((cz >> b) & 1) << (3 * b + 2));
  return k;
}

__device__ __forceinline__ unsigned int cell_of(float x, float y, float z) {
  int cx = min(63, max(0, (int)(x * 64.0f)));
  int cy = min(63, max(0, (int)(y * 64.0f)));
  int cz = min(63, max(0, (int)(z * 64.0f)));
  return morton6(cx, cy, cz);
}

// ---------------- fused build_compact + keys_hist ----------------
__global__ __launch_bounds__(256) void build_and_hist(
    const float* __restrict__ table, float2* __restrict__ compact,
    const float* __restrict__ pos, unsigned int* __restrict__ hist,
    ResParams P, int B, int nbuild)
{
  __shared__ nfloat2 rowbuf[MAX_RES];
  int b = blockIdx.x;

  if (b < nbuild) {
    int li = 0;
    #pragma unroll
    for (int k = 1; k < NLC; ++k) if (b >= P.bstart[k]) li = k;
    int l = LC_LO + li;
    int res = P.res[l];
    int W = res + 1;
    int rem = b - P.bstart[li];
    int p = rem / W;
    int v = rem - p * W;
    const float fres = (float)res;

    int cv = (int)(__fmul_rn(__fdiv_rn((float)v, fres), 2047.0f));
    const float* src = table + (size_t)p * (MAX_RES * MAX_RES * 2) + (size_t)(cv << 11) * 2;

    const nfloat4* src4 = reinterpret_cast<const nfloat4*>(src);
    #pragma unroll
    for (int j = (int)threadIdx.x; j < MAX_RES / 2; j += 256) {
      nfloat4 r = src4[j];
      rowbuf[j * 2]     = nfloat2{r.x, r.y};
      rowbuf[j * 2 + 1] = nfloat2{r.z, r.w};
    }
    __syncthreads();

    float2* dst = compact + (P.coff[l] + p * P.S[l] + v * W);
    for (int u = (int)threadIdx.x; u < W; u += 256) {
      int cu = (int)(__fmul_rn(__fdiv_rn((float)u, fres), 2047.0f));
      nfloat2 e = rowbuf[cu];
      dst[u] = make_float2(e.x, e.y);
    }
  } else {
    int i = (b - nbuild) * 256 + (int)threadIdx.x;
    if (i < B)
      atomicAdd(&hist[cell_of(pos[i*3], pos[i*3+1], pos[i*3+2])], 1u);
  }
}

// ---------------- 2-level parallel scan ----------------
__global__ __launch_bounds__(256) void scan_partial(const unsigned int* __restrict__ hist,
                                                    unsigned int* __restrict__ offs,
                                                    unsigned int* __restrict__ partials) {
  __shared__ unsigned int sh[256];
  int tid = (int)threadIdx.x;
  int c = blockIdx.x * 256 + tid;
  unsigned int v = hist[c];
  sh[tid] = v;
  __syncthreads();
  #pragma unroll
  for (int off = 1; off < 256; off <<= 1) {
    unsigned int u = (tid >= off) ? sh[tid - off] : 0u;
    __syncthreads();
    sh[tid] += u;
    __syncthreads();
  }
  offs[c] = sh[tid] - v;
  if (tid == 255) partials[blockIdx.x] = sh[255];
}

__global__ __launch_bounds__(1024) void scan_roots(const unsigned int* __restrict__ partials,
                                                   unsigned int* __restrict__ roots) {
  __shared__ unsigned int sh[NSEG];
  int tid = (int)threadIdx.x;
  unsigned int v = partials[tid];
  sh[tid] = v;
  __syncthreads();
  #pragma unroll
  for (int off = 1; off < NSEG; off <<= 1) {
    unsigned int u = (tid >= off) ? sh[tid - off] : 0u;
    __syncthreads();
    sh[tid] += u;
    __syncthreads();
  }
  roots[tid] = sh[tid] - v;
}

__global__ __launch_bounds__(256) void scatter_kernel(const float* __restrict__ pos,
                                                      unsigned int* __restrict__ offs,
                                                      const unsigned int* __restrict__ roots,
                                                      nfloat4* __restrict__ sorted, int B) {
  int i = blockIdx.x * 256 + (int)threadIdx.x;
  if (i >= B) return;
  float x = pos[i*3], y = pos[i*3+1], z = pos[i*3+2];
  unsigned int k = cell_of(x, y, z);
  unsigned int slot = roots[k >> 8] + atomicAdd(&offs[k], 1u);
  nfloat4 v = {x, y, z, __int_as_float(i)};
  sorted[slot] = v;
}

// ---------------- main encode ----------------
// R19 + direct per-level LDS sink: prod0/prod1 go straight into obuf (no
// o0/o1 register arrays, no end-of-loop copy) -> ~32 fewer VGPR -> more
// resident waves for latency hiding. Transposed store unchanged: each wave
// stores 8 full 128B lines per instruction.
#define OSTRIDE 36   // floats; 144B rows, 16B-aligned

template <bool USE_COMPACT>
__global__ __launch_bounds__(256) void triplane_main(
    const nfloat4* __restrict__ sorted,
    const float* __restrict__ table,
    const float2* __restrict__ compact,
    float* __restrict__ out,
    ResParams P, int B, int nwg)
{
  __shared__ float obuf[256 * OSTRIDE];
  __shared__ int   oorig[256];

  int wg = blockIdx.x;
  int q = nwg >> 3, r = nwg & 7;
  int xcd = wg & 7, idx = wg >> 3;
  int swz = (xcd < r) ? xcd * (q + 1) + idx : r * (q + 1) + (xcd - r) * q + idx;
  int t = swz * 256 + (int)threadIdx.x;
  if (t >= B) return;

  nfloat4 s = sorted[t];
  float x = s.x, y = s.y, z = s.z;
  int orig = __float_as_int(s.w);

  float uarr[3] = {x, y, z};
  float varr[3] = {y, z, x};

  int tid = (int)threadIdx.x;
  float* myrow = &obuf[tid * OSTRIDE];
  oorig[tid] = orig;

  #pragma unroll
  for (int l = 0; l < LEVELS; ++l) {
    const int   res   = P.res[l];
    const float resm1 = (float)(res - 1);
    const float fres  = (float)res;
    const bool  cpath = USE_COMPACT && (l >= LC_LO && l <= LC_HI);

    float prod0 = 1.0f, prod1 = 1.0f;

    #pragma unroll
    for (int p = 0; p < 3; ++p) {
      float pu = __fadd_rn(__fmul_rn(uarr[p], resm1), 0.5f);
      float pv = __fadd_rn(__fmul_rn(varr[p], resm1), 0.5f);
      float gu = floorf(pu), gv = floorf(pv);
      float fu = __fsub_rn(pu, gu);
      float fv = __fsub_rn(pv, gv);

      float f00x, f00y, f10x, f10y, f01x, f01y, f11x, f11y;

      if (cpath) {
        int iu = (int)gu, iv = (int)gv;
        int W = res + 1;
        const float2* lv = compact + (P.coff[l] + p * P.S[l]);
        int i0 = iv * W + iu;
        const nfloat4 r0 = *reinterpret_cast<const nfloat4*>(lv + i0);
        const nfloat4 r1 = *reinterpret_cast<const nfloat4*>(lv + i0 + W);
        f00x = r0.x; f00y = r0.y; f10x = r0.z; f10y = r0.w;
        f01x = r1.x; f01y = r1.y; f11x = r1.z; f11y = r1.w;
      } else {
        float gu1 = __fadd_rn(gu, 1.0f);
        float gv1 = __fadd_rn(gv, 1.0f);
        int cou0 = (int)(__fmul_rn(__fdiv_rn(gu,  fres), 2047.0f));
        int cou1 = (int)(__fmul_rn(__fdiv_rn(gu1, fres), 2047.0f));
        int cov0 = (int)(__fmul_rn(__fdiv_rn(gv,  fres), 2047.0f));
        int cov1 = (int)(__fmul_rn(__fdiv_rn(gv1, fres), 2047.0f));

        const float* plane = table + (size_t)p * (MAX_RES * MAX_RES * 2);

        if (l == 15) {
          const nfloat4 r0 = *reinterpret_cast<const nfloat4*>(plane + (size_t)(cou0 + (cov0 << 11)) * 2);
          const nfloat4 r1 = *reinterpret_cast<const nfloat4*>(plane + (size_t)(cou0 + (cov1 << 11)) * 2);
          const bool adj = (cou1 != cou0);
          f00x = r0.x; f00y = r0.y;
          f10x = adj ? r0.z : r0.x;  f10y = adj ? r0.w : r0.y;
          f01x = r1.x; f01y = r1.y;
          f11x = adj ? r1.z : r1.x;  f11y = adj ? r1.w : r1.y;
        } else {
          const float2 f00 = *reinterpret_cast<const float2*>(plane + (size_t)(cou0 + (cov0 << 11)) * 2);
          const float2 f10 = *reinterpret_cast<const float2*>(plane + (size_t)(cou1 + (cov0 << 11)) * 2);
          const float2 f01 = *reinterpret_cast<const float2*>(plane + (size_t)(cou0 + (cov1 << 11)) * 2);
          const float2 f11 = *reinterpret_cast<const float2*>(plane + (size_t)(cou1 + (cov1 << 11)) * 2);
          f00x = f00.x; f00y = f00.y; f10x = f10.x; f10y = f10.y;
          f01x = f01.x; f01y = f01.y; f11x = f11.x; f11y = f11.y;
        }
      }

      float w00 = (1.0f - fu) * (1.0f - fv);
      float w10 = fu * (1.0f - fv);
      float w01 = (1.0f - fu) * fv;
      float w11 = fu * fv;

      float a0 = 0.0f, a1 = 0.0f;
      a0 += w00 * f00x;  a1 += w00 * f00y;
      a0 += w10 * f10x;  a1 += w10 * f10y;
      a0 += w01 * f01x;  a1 += w01 * f01y;
      a0 += w11 * f11x;  a1 += w11 * f11y;

      prod0 *= a0;
      prod1 *= a1;
    }

    // direct sink: no register arrays, no final copy
    myrow[l]      = prod0;
    myrow[16 + l] = prod1;
  }

  // ---- wave-transposed store (same-wave LDS ordering via lgkmcnt) ----
  int lane  = tid & 63;
  int wbase = tid & ~63;
  #pragma unroll
  for (int sI = 0; sI < 8; ++sI) {
    int ts = wbase + sI * 8 + (lane >> 3);
    int j  = lane & 7;
    const nfloat4 v = *reinterpret_cast<const nfloat4*>(&obuf[ts * OSTRIDE + j * 4]);
    int og = oorig[ts];
    *reinterpret_cast<nfloat4*>(out + (size_t)og * 32 + j * 4) = v;
  }
}

extern "C" void kernel_launch(void* const* d_in, const int* in_sizes, int n_in,
                              void* d_out, int out_size, void* d_ws, size_t ws_size,
                              hipStream_t stream) {
  const float* positions = (const float*)d_in[0];
  const float* table     = (const float*)d_in[1];
  float* out             = (float*)d_out;
  int B = in_sizes[0] / 3;

  ResParams P;
  const double LOG_B = log(2048.0 / 16.0) / (double)(LEVELS - 1);
  int runoff = 0;
  for (int l = 0; l < LEVELS; ++l) {
    double scale = 16.0 * exp((double)l * LOG_B) - 1.0;
    P.res[l] = (int)ceil(scale) + 1;
    P.coff[l] = 0; P.S[l] = 0;
  }
  int nbuild = 0;
  for (int li = 0; li < NLC; ++li) {
    int l = LC_LO + li;
    int W = P.res[l] + 1;
    P.S[l] = W * W;
    P.coff[l] = runoff;
    runoff += 3 * P.S[l];
    P.bstart[li] = nbuild;
    nbuild += 3 * W;
  }
  P.bstart[NLC] = nbuild;

  int nwg = (B + 255) / 256;

  size_t off_hist    = 0;
  size_t off_offs    = off_hist + (size_t)NCELLS * 4;
  size_t off_part    = off_offs + (size_t)NCELLS * 4;
  size_t off_roots   = off_part + (size_t)NSEG * 4;
  size_t off_sorted  = ((off_roots + (size_t)NSEG * 4) + 255) & ~(size_t)255;
  size_t off_compact = off_sorted + (size_t)B * 16;
  size_t need_sort   = off_compact;
  size_t need_all    = off_compact + (size_t)runoff * 8;

  if (ws_size < need_sort) return;

  unsigned int* hist  = (unsigned int*)((char*)d_ws + off_hist);
  unsigned int* offs  = (unsigned int*)((char*)d_ws + off_offs);
  unsigned int* part  = (unsigned int*)((char*)d_ws + off_part);
  unsigned int* roots = (unsigned int*)((char*)d_ws + off_roots);
  nfloat4*      srt   = (nfloat4*)((char*)d_ws + off_sorted);
  float2*       cmp   = (float2*)((char*)d_ws + off_compact);

  const bool use_compact = (ws_size >= need_all);
  const int nb = use_compact ? nbuild : 0;

  hipMemsetAsync(hist, 0, (size_t)NCELLS * 4, stream);
  hipLaunchKernelGGL(build_and_hist, dim3(nb + nwg), dim3(256), 0, stream,
                     table, cmp, positions, hist, P, B, nb);
  hipLaunchKernelGGL(scan_partial, dim3(NSEG), dim3(256), 0, stream, hist, offs, part);
  hipLaunchKernelGGL(scan_roots, dim3(1), dim3(NSEG), 0, stream, part, roots);
  hipLaunchKernelGGL(scatter_kernel, dim3(nwg), dim3(256), 0, stream,
                     positions, offs, roots, srt, B);

  if (use_compact) {
    hipLaunchKernelGGL((triplane_main<true>), dim3(nwg), dim3(256), 0, stream,
                       srt, table, cmp, out, P, B, nwg);
  } else {
    hipLaunchKernelGGL((triplane_main<false>), dim3(nwg), dim3(256), 0, stream,
                       srt, table, cmp, out, P, B, nwg);
  }
}

// Round 21
// 397.778 us; speedup vs baseline: 1.1185x; 1.1185x over previous
//
#include <hip/hip_runtime.h>
#include <math.h>

#define LEVELS 16
#define MAX_RES 2048
#define NCELL_BITS 6
#define NCELLS (1 << (3 * NCELL_BITS))   // 262144 cells (64^3), ~4 points/cell
#define NSEG   (NCELLS / 256)            // 1024 scan segments
#define LC_LO 9
#define LC_HI 12
#define NLC (LC_HI - LC_LO + 1)

typedef float nfloat4 __attribute__((ext_vector_type(4)));
typedef float nfloat2 __attribute__((ext_vector_type(2)));

struct ResParams {
  int res[LEVELS];
  int coff[LEVELS];
  int S[LEVELS];
  int bstart[NLC + 1];
};

// ---------------- sort helpers ----------------

__device__ __forceinline__ unsigned int morton6(int cx, int cy, int cz) {
  unsigned int k = 0;
  #pragma unroll
  for (int b = 0; b < NCELL_BITS; ++b)
    k |= (((cx >> b) & 1) << (3 * b)) | (((cy >> b) & 1) << (3 * b + 1)) |
         (((cz >> b) & 1) << (3 * b + 2));
  return k;
}

__device__ __forceinline__ unsigned int cell_of(float x, float y, float z) {
  int cx = min(63, max(0, (int)(x * 64.0f)));
  int cy = min(63, max(0, (int)(y * 64.0f)));
  int cz = min(63, max(0, (int)(z * 64.0f)));
  return morton6(cx, cy, cz);
}

// ---------------- fused build_compact + keys_hist ----------------
__global__ __launch_bounds__(256) void build_and_hist(
    const float* __restrict__ table, float2* __restrict__ compact,
    const float* __restrict__ pos, unsigned int* __restrict__ hist,
    ResParams P, int B, int nbuild)
{
  __shared__ nfloat2 rowbuf[MAX_RES];
  int b = blockIdx.x;

  if (b < nbuild) {
    int li = 0;
    #pragma unroll
    for (int k = 1; k < NLC; ++k) if (b >= P.bstart[k]) li = k;
    int l = LC_LO + li;
    int res = P.res[l];
    int W = res + 1;
    int rem = b - P.bstart[li];
    int p = rem / W;
    int v = rem - p * W;
    const float fres = (float)res;

    int cv = (int)(__fmul_rn(__fdiv_rn((float)v, fres), 2047.0f));
    const float* src = table + (size_t)p * (MAX_RES * MAX_RES * 2) + (size_t)(cv << 11) * 2;

    const nfloat4* src4 = reinterpret_cast<const nfloat4*>(src);
    #pragma unroll
    for (int j = (int)threadIdx.x; j < MAX_RES / 2; j += 256) {
      nfloat4 r = src4[j];
      rowbuf[j * 2]     = nfloat2{r.x, r.y};
      rowbuf[j * 2 + 1] = nfloat2{r.z, r.w};
    }
    __syncthreads();

    float2* dst = compact + (P.coff[l] + p * P.S[l] + v * W);
    for (int u = (int)threadIdx.x; u < W; u += 256) {
      int cu = (int)(__fmul_rn(__fdiv_rn((float)u, fres), 2047.0f));
      nfloat2 e = rowbuf[cu];
      dst[u] = make_float2(e.x, e.y);
    }
  } else {
    int i = (b - nbuild) * 256 + (int)threadIdx.x;
    if (i < B)
      atomicAdd(&hist[cell_of(pos[i*3], pos[i*3+1], pos[i*3+2])], 1u);
  }
}

// ---------------- 2-level parallel scan ----------------
__global__ __launch_bounds__(256) void scan_partial(const unsigned int* __restrict__ hist,
                                                    unsigned int* __restrict__ offs,
                                                    unsigned int* __restrict__ partials) {
  __shared__ unsigned int sh[256];
  int tid = (int)threadIdx.x;
  int c = blockIdx.x * 256 + tid;
  unsigned int v = hist[c];
  sh[tid] = v;
  __syncthreads();
  #pragma unroll
  for (int off = 1; off < 256; off <<= 1) {
    unsigned int u = (tid >= off) ? sh[tid - off] : 0u;
    __syncthreads();
    sh[tid] += u;
    __syncthreads();
  }
  offs[c] = sh[tid] - v;
  if (tid == 255) partials[blockIdx.x] = sh[255];
}

__global__ __launch_bounds__(1024) void scan_roots(const unsigned int* __restrict__ partials,
                                                   unsigned int* __restrict__ roots) {
  __shared__ unsigned int sh[NSEG];
  int tid = (int)threadIdx.x;
  unsigned int v = partials[tid];
  sh[tid] = v;
  __syncthreads();
  #pragma unroll
  for (int off = 1; off < NSEG; off <<= 1) {
    unsigned int u = (tid >= off) ? sh[tid - off] : 0u;
    __syncthreads();
    sh[tid] += u;
    __syncthreads();
  }
  roots[tid] = sh[tid] - v;
}

__global__ __launch_bounds__(256) void scatter_kernel(const float* __restrict__ pos,
                                                      unsigned int* __restrict__ offs,
                                                      const unsigned int* __restrict__ roots,
                                                      nfloat4* __restrict__ sorted, int B) {
  int i = blockIdx.x * 256 + (int)threadIdx.x;
  if (i >= B) return;
  float x = pos[i*3], y = pos[i*3+1], z = pos[i*3+2];
  unsigned int k = cell_of(x, y, z);
  unsigned int slot = roots[k >> 8] + atomicAdd(&offs[k], 1u);
  nfloat4 v = {x, y, z, __int_as_float(i)};
  sorted[slot] = v;
}

// ---------------- main encode ----------------
// R19 (best measured): register result arrays (deep per-wave ILP, 156 VGPR,
// low occupancy -> small concurrent footprint, FETCH 378MB) + wave-transposed
// store via LDS: each wave stores 8 full 128B lines per instruction (8 lanes
// x 16B contiguous per line) instead of 64 partial-line groups.
#define OSTRIDE 36   // floats; 144B rows, 16B-aligned

template <bool USE_COMPACT>
__global__ __launch_bounds__(256) void triplane_main(
    const nfloat4* __restrict__ sorted,
    const float* __restrict__ table,
    const float2* __restrict__ compact,
    float* __restrict__ out,
    ResParams P, int B, int nwg)
{
  __shared__ float obuf[256 * OSTRIDE];
  __shared__ int   oorig[256];

  int wg = blockIdx.x;
  int q = nwg >> 3, r = nwg & 7;
  int xcd = wg & 7, idx = wg >> 3;
  int swz = (xcd < r) ? xcd * (q + 1) + idx : r * (q + 1) + (xcd - r) * q + idx;
  int t = swz * 256 + (int)threadIdx.x;
  if (t >= B) return;

  nfloat4 s = sorted[t];
  float x = s.x, y = s.y, z = s.z;
  int orig = __float_as_int(s.w);

  float uarr[3] = {x, y, z};
  float varr[3] = {y, z, x};

  float o0[LEVELS], o1[LEVELS];

  #pragma unroll
  for (int l = 0; l < LEVELS; ++l) {
    const int   res   = P.res[l];
    const float resm1 = (float)(res - 1);
    const float fres  = (float)res;
    const bool  cpath = USE_COMPACT && (l >= LC_LO && l <= LC_HI);

    float prod0 = 1.0f, prod1 = 1.0f;

    #pragma unroll
    for (int p = 0; p < 3; ++p) {
      float pu = __fadd_rn(__fmul_rn(uarr[p], resm1), 0.5f);
      float pv = __fadd_rn(__fmul_rn(varr[p], resm1), 0.5f);
      float gu = floorf(pu), gv = floorf(pv);
      float fu = __fsub_rn(pu, gu);
      float fv = __fsub_rn(pv, gv);

      float f00x, f00y, f10x, f10y, f01x, f01y, f11x, f11y;

      if (cpath) {
        int iu = (int)gu, iv = (int)gv;
        int W = res + 1;
        const float2* lv = compact + (P.coff[l] + p * P.S[l]);
        int i0 = iv * W + iu;
        const nfloat4 r0 = *reinterpret_cast<const nfloat4*>(lv + i0);
        const nfloat4 r1 = *reinterpret_cast<const nfloat4*>(lv + i0 + W);
        f00x = r0.x; f00y = r0.y; f10x = r0.z; f10y = r0.w;
        f01x = r1.x; f01y = r1.y; f11x = r1.z; f11y = r1.w;
      } else {
        float gu1 = __fadd_rn(gu, 1.0f);
        float gv1 = __fadd_rn(gv, 1.0f);
        int cou0 = (int)(__fmul_rn(__fdiv_rn(gu,  fres), 2047.0f));
        int cou1 = (int)(__fmul_rn(__fdiv_rn(gu1, fres), 2047.0f));
        int cov0 = (int)(__fmul_rn(__fdiv_rn(gv,  fres), 2047.0f));
        int cov1 = (int)(__fmul_rn(__fdiv_rn(gv1, fres), 2047.0f));

        const float* plane = table + (size_t)p * (MAX_RES * MAX_RES * 2);

        if (l == 15) {
          const nfloat4 r0 = *reinterpret_cast<const nfloat4*>(plane + (size_t)(cou0 + (cov0 << 11)) * 2);
          const nfloat4 r1 = *reinterpret_cast<const nfloat4*>(plane + (size_t)(cou0 + (cov1 << 11)) * 2);
          const bool adj = (cou1 != cou0);
          f00x = r0.x; f00y = r0.y;
          f10x = adj ? r0.z : r0.x;  f10y = adj ? r0.w : r0.y;
          f01x = r1.x; f01y = r1.y;
          f11x = adj ? r1.z : r1.x;  f11y = adj ? r1.w : r1.y;
        } else {
          const float2 f00 = *reinterpret_cast<const float2*>(plane + (size_t)(cou0 + (cov0 << 11)) * 2);
          const float2 f10 = *reinterpret_cast<const float2*>(plane + (size_t)(cou1 + (cov0 << 11)) * 2);
          const float2 f01 = *reinterpret_cast<const float2*>(plane + (size_t)(cou0 + (cov1 << 11)) * 2);
          const float2 f11 = *reinterpret_cast<const float2*>(plane + (size_t)(cou1 + (cov1 << 11)) * 2);
          f00x = f00.x; f00y = f00.y; f10x = f10.x; f10y = f10.y;
          f01x = f01.x; f01y = f01.y; f11x = f11.x; f11y = f11.y;
        }
      }

      float w00 = (1.0f - fu) * (1.0f - fv);
      float w10 = fu * (1.0f - fv);
      float w01 = (1.0f - fu) * fv;
      float w11 = fu * fv;

      float a0 = 0.0f, a1 = 0.0f;
      a0 += w00 * f00x;  a1 += w00 * f00y;
      a0 += w10 * f10x;  a1 += w10 * f10y;
      a0 += w01 * f01x;  a1 += w01 * f01y;
      a0 += w11 * f11x;  a1 += w11 * f11y;

      prod0 *= a0;
      prod1 *= a1;
    }

    o0[l] = prod0;
    o1[l] = prod1;
  }

  // ---- wave-transposed store ----
  int tid  = (int)threadIdx.x;
  float* myrow = &obuf[tid * OSTRIDE];
  #pragma unroll
  for (int l = 0; l < LEVELS; ++l) {
    myrow[l]          = o0[l];
    myrow[16 + l]     = o1[l];
  }
  oorig[tid] = orig;

  int lane  = tid & 63;
  int wbase = tid & ~63;
  #pragma unroll
  for (int sI = 0; sI < 8; ++sI) {
    int ts = wbase + sI * 8 + (lane >> 3);   // which thread's line this lane helps write
    int j  = lane & 7;                       // which 16B chunk of that line
    const nfloat4 v = *reinterpret_cast<const nfloat4*>(&obuf[ts * OSTRIDE + j * 4]);
    int og = oorig[ts];
    *reinterpret_cast<nfloat4*>(out + (size_t)og * 32 + j * 4) = v;
  }
}

extern "C" void kernel_launch(void* const* d_in, const int* in_sizes, int n_in,
                              void* d_out, int out_size, void* d_ws, size_t ws_size,
                              hipStream_t stream) {
  const float* positions = (const float*)d_in[0];
  const float* table     = (const float*)d_in[1];
  float* out             = (float*)d_out;
  int B = in_sizes[0] / 3;

  ResParams P;
  const double LOG_B = log(2048.0 / 16.0) / (double)(LEVELS - 1);
  int runoff = 0;
  for (int l = 0; l < LEVELS; ++l) {
    double scale = 16.0 * exp((double)l * LOG_B) - 1.0;
    P.res[l] = (int)ceil(scale) + 1;
    P.coff[l] = 0; P.S[l] = 0;
  }
  int nbuild = 0;
  for (int li = 0; li < NLC; ++li) {
    int l = LC_LO + li;
    int W = P.res[l] + 1;
    P.S[l] = W * W;
    P.coff[l] = runoff;
    runoff += 3 * P.S[l];
    P.bstart[li] = nbuild;
    nbuild += 3 * W;
  }
  P.bstart[NLC] = nbuild;

  int nwg = (B + 255) / 256;

  size_t off_hist    = 0;
  size_t off_offs    = off_hist + (size_t)NCELLS * 4;
  size_t off_part    = off_offs + (size_t)NCELLS * 4;
  size_t off_roots   = off_part + (size_t)NSEG * 4;
  size_t off_sorted  = ((off_roots + (size_t)NSEG * 4) + 255) & ~(size_t)255;
  size_t off_compact = off_sorted + (size_t)B * 16;
  size_t need_sort   = off_compact;
  size_t need_all    = off_compact + (size_t)runoff * 8;

  if (ws_size < need_sort) return;

  unsigned int* hist  = (unsigned int*)((char*)d_ws + off_hist);
  unsigned int* offs  = (unsigned int*)((char*)d_ws + off_offs);
  unsigned int* part  = (unsigned int*)((char*)d_ws + off_part);
  unsigned int* roots = (unsigned int*)((char*)d_ws + off_roots);
  nfloat4*      srt   = (nfloat4*)((char*)d_ws + off_sorted);
  float2*       cmp   = (float2*)((char*)d_ws + off_compact);

  const bool use_compact = (ws_size >= need_all);
  const int nb = use_compact ? nbuild : 0;

  hipMemsetAsync(hist, 0, (size_t)NCELLS * 4, stream);
  hipLaunchKernelGGL(build_and_hist, dim3(nb + nwg), dim3(256), 0, stream,
                     table, cmp, positions, hist, P, B, nb);
  hipLaunchKernelGGL(scan_partial, dim3(NSEG), dim3(256), 0, stream, hist, offs, part);
  hipLaunchKernelGGL(scan_roots, dim3(1), dim3(NSEG), 0, stream, part, roots);
  hipLaunchKernelGGL(scatter_kernel, dim3(nwg), dim3(256), 0, stream,
                     positions, offs, roots, srt, B);

  if (use_compact) {
    hipLaunchKernelGGL((triplane_main<true>), dim3(nwg), dim3(256), 0, stream,
                       srt, table, cmp, out, P, B, nwg);
  } else {
    hipLaunchKernelGGL((triplane_main<false>), dim3(nwg), dim3(256), 0, stream,
                       srt, table, cmp, out, P, B, nwg);
  }
}